// Round 1
// baseline (3728.275 us; speedup 1.0000x reference)
//
#include <hip/hip_runtime.h>
#include <math.h>

#define R_TOTAL 64000   // B*G*T*N
#define D 256
#define DFF 1024
#define MDIM 128
#define NB 500
#define TT 16
#define GG 4
#define BB 2
#define NTRACK (BB*GG*NB)   // 4000

__device__ __forceinline__ float gelu_f(float x) {
    // jax.nn.gelu(approximate=True): 0.5*x*(1+tanh(sqrt(2/pi)*(x+0.044715*x^3)))
    float x3 = x * x * x;
    float t = tanhf(0.7978845608028654f * (x + 0.044715f * x3));
    return 0.5f * x * (1.0f + t);
}

// ---------------------------------------------------------------------------
// Fused FFN: Y = X + gelu(X@W1 + B1)@W2 + B2   (residual = X, safe for Y==X)
// Block: 256 threads, BR=16 rows. Hidden processed in 4 chunks of 256 via LDS.
// ---------------------------------------------------------------------------
template<int BR>
__global__ __launch_bounds__(256)
void ffn_kernel(const float* __restrict__ X,
                const float* __restrict__ W1, const float* __restrict__ B1,
                const float* __restrict__ W2, const float* __restrict__ B2,
                float* __restrict__ Y)
{
    __shared__ float xs[BR][D];
    __shared__ float hs[BR][256];
    const int t = threadIdx.x;
    const int row0 = blockIdx.x * BR;

    for (int i = t; i < BR * D; i += 256) {
        int r = i >> 8, c = i & 255;
        xs[r][c] = X[(size_t)(row0 + r) * D + c];
    }
    __syncthreads();

    float a2[BR];
#pragma unroll
    for (int r = 0; r < BR; ++r) a2[r] = 0.f;

    for (int c = 0; c < DFF / 256; ++c) {
        const int hc = c * 256 + t;
        float a1[BR];
#pragma unroll
        for (int r = 0; r < BR; ++r) a1[r] = 0.f;

        const float* w1p = W1 + hc;
        for (int k = 0; k < D; k += 4) {
            float w0 = w1p[(size_t)(k + 0) * DFF];
            float w1v = w1p[(size_t)(k + 1) * DFF];
            float w2v = w1p[(size_t)(k + 2) * DFF];
            float w3 = w1p[(size_t)(k + 3) * DFF];
#pragma unroll
            for (int r = 0; r < BR; ++r) {
                float4 xv = *reinterpret_cast<const float4*>(&xs[r][k]);
                a1[r] = fmaf(xv.x, w0, a1[r]);
                a1[r] = fmaf(xv.y, w1v, a1[r]);
                a1[r] = fmaf(xv.z, w2v, a1[r]);
                a1[r] = fmaf(xv.w, w3, a1[r]);
            }
        }
        float b1v = B1[hc];
#pragma unroll
        for (int r = 0; r < BR; ++r) hs[r][t] = gelu_f(a1[r] + b1v);
        __syncthreads();

        const float* w2p = W2 + (size_t)c * 256 * D + t;
        for (int k = 0; k < 256; k += 4) {
            float w0 = w2p[(size_t)(k + 0) * D];
            float w1v = w2p[(size_t)(k + 1) * D];
            float w2v = w2p[(size_t)(k + 2) * D];
            float w3 = w2p[(size_t)(k + 3) * D];
#pragma unroll
            for (int r = 0; r < BR; ++r) {
                float4 hv = *reinterpret_cast<const float4*>(&hs[r][k]);
                a2[r] = fmaf(hv.x, w0, a2[r]);
                a2[r] = fmaf(hv.y, w1v, a2[r]);
                a2[r] = fmaf(hv.z, w2v, a2[r]);
                a2[r] = fmaf(hv.w, w3, a2[r]);
            }
        }
        __syncthreads();
    }

    float b2v = B2[t];
#pragma unroll
    for (int r = 0; r < BR; ++r) {
        Y[(size_t)(row0 + r) * D + t] = xs[r][t] + a2[r] + b2v;
    }
}

// ---------------------------------------------------------------------------
// LayerNorm over last dim (256). One wave per row, float4 per lane. In-place OK.
// ---------------------------------------------------------------------------
__global__ __launch_bounds__(256)
void ln_kernel(const float* __restrict__ X, const float* __restrict__ g,
               const float* __restrict__ b, float* __restrict__ Y)
{
    const int lane = threadIdx.x & 63;
    const int wave = threadIdx.x >> 6;
    const size_t row = (size_t)blockIdx.x * 4 + wave;
    float4 v = reinterpret_cast<const float4*>(X + row * D)[lane];
    float s = v.x + v.y + v.z + v.w;
#pragma unroll
    for (int m = 32; m >= 1; m >>= 1) s += __shfl_xor(s, m, 64);
    float mu = s * (1.0f / 256.0f);
    float4 d = {v.x - mu, v.y - mu, v.z - mu, v.w - mu};
    float q = d.x * d.x + d.y * d.y + d.z * d.z + d.w * d.w;
#pragma unroll
    for (int m = 32; m >= 1; m >>= 1) q += __shfl_xor(q, m, 64);
    float var = q * (1.0f / 256.0f);
    float sc = 1.0f / sqrtf(var + 1e-5f);
    float4 gv = reinterpret_cast<const float4*>(g)[lane];
    float4 bv = reinterpret_cast<const float4*>(b)[lane];
    float4 o = {d.x * sc * gv.x + bv.x, d.y * sc * gv.y + bv.y,
                d.z * sc * gv.z + bv.z, d.w * sc * gv.w + bv.w};
    reinterpret_cast<float4*>(Y + row * D)[lane] = o;
}

// ---------------------------------------------------------------------------
// Motion MLP: in = concat(x, boxes, vel) (264) -> gelu@mw1(128) -> gelu@mw2(128)
//             -> @mw3(128) * mask.  128 threads, BR=16 rows.
// ---------------------------------------------------------------------------
template<int BR>
__global__ __launch_bounds__(128)
void motion_kernel(const float* __restrict__ x1, const float* __restrict__ boxes,
                   const int* __restrict__ masks,
                   const float* __restrict__ MW1, const float* __restrict__ MB1,
                   const float* __restrict__ MW2, const float* __restrict__ MB2,
                   const float* __restrict__ MW3, const float* __restrict__ MB3,
                   float* __restrict__ Mout)
{
    __shared__ float ins[BR][264];
    __shared__ float h1[BR][MDIM];
    __shared__ float h2[BR][MDIM];
    const int t = threadIdx.x;
    const int row0 = blockIdx.x * BR;

    for (int i = t; i < BR * 264; i += 128) {
        int r = i / 264, c = i % 264;
        int row = row0 + r;
        float v;
        if (c < 256) {
            v = x1[(size_t)row * D + c];
        } else if (c < 260) {
            v = boxes[(size_t)row * 4 + (c - 256)];
        } else {
            int tt = (row / NB) % TT;
            int prev = (tt == 0) ? row : row - NB;
            int j = c - 260;
            v = boxes[(size_t)row * 4 + j] - boxes[(size_t)prev * 4 + j];
        }
        ins[r][c] = v;
    }
    __syncthreads();

    float a[BR];
#pragma unroll
    for (int r = 0; r < BR; ++r) a[r] = 0.f;
    for (int k = 0; k < 264; k += 4) {
        float w0 = MW1[(size_t)(k + 0) * MDIM + t];
        float w1 = MW1[(size_t)(k + 1) * MDIM + t];
        float w2 = MW1[(size_t)(k + 2) * MDIM + t];
        float w3 = MW1[(size_t)(k + 3) * MDIM + t];
#pragma unroll
        for (int r = 0; r < BR; ++r) {
            float4 xv = *reinterpret_cast<const float4*>(&ins[r][k]);
            a[r] = fmaf(xv.x, w0, a[r]);
            a[r] = fmaf(xv.y, w1, a[r]);
            a[r] = fmaf(xv.z, w2, a[r]);
            a[r] = fmaf(xv.w, w3, a[r]);
        }
    }
    float bb1 = MB1[t];
#pragma unroll
    for (int r = 0; r < BR; ++r) h1[r][t] = gelu_f(a[r] + bb1);
    __syncthreads();

#pragma unroll
    for (int r = 0; r < BR; ++r) a[r] = 0.f;
    for (int k = 0; k < MDIM; k += 4) {
        float w0 = MW2[(size_t)(k + 0) * MDIM + t];
        float w1 = MW2[(size_t)(k + 1) * MDIM + t];
        float w2 = MW2[(size_t)(k + 2) * MDIM + t];
        float w3 = MW2[(size_t)(k + 3) * MDIM + t];
#pragma unroll
        for (int r = 0; r < BR; ++r) {
            float4 xv = *reinterpret_cast<const float4*>(&h1[r][k]);
            a[r] = fmaf(xv.x, w0, a[r]);
            a[r] = fmaf(xv.y, w1, a[r]);
            a[r] = fmaf(xv.z, w2, a[r]);
            a[r] = fmaf(xv.w, w3, a[r]);
        }
    }
    float bb2 = MB2[t];
#pragma unroll
    for (int r = 0; r < BR; ++r) h2[r][t] = gelu_f(a[r] + bb2);
    __syncthreads();

#pragma unroll
    for (int r = 0; r < BR; ++r) a[r] = 0.f;
    for (int k = 0; k < MDIM; k += 4) {
        float w0 = MW3[(size_t)(k + 0) * MDIM + t];
        float w1 = MW3[(size_t)(k + 1) * MDIM + t];
        float w2 = MW3[(size_t)(k + 2) * MDIM + t];
        float w3 = MW3[(size_t)(k + 3) * MDIM + t];
#pragma unroll
        for (int r = 0; r < BR; ++r) {
            float4 xv = *reinterpret_cast<const float4*>(&h2[r][k]);
            a[r] = fmaf(xv.x, w0, a[r]);
            a[r] = fmaf(xv.y, w1, a[r]);
            a[r] = fmaf(xv.z, w2, a[r]);
            a[r] = fmaf(xv.w, w3, a[r]);
        }
    }
    float bb3 = MB3[t];
#pragma unroll
    for (int r = 0; r < BR; ++r) {
        float mf = (masks[row0 + r] != 0) ? 1.0f : 0.0f;
        Mout[(size_t)(row0 + r) * MDIM + t] = (a[r] + bb3) * mf;
    }
}

// ---------------------------------------------------------------------------
// Fusion: f = concat(x(256), m(128)) -> relu(f@fw1+fb1)@fw2+fb2. Y==x1 is safe.
// ---------------------------------------------------------------------------
template<int BR>
__global__ __launch_bounds__(256)
void fusion_kernel(const float* __restrict__ x1, const float* __restrict__ m,
                   const float* __restrict__ FW1, const float* __restrict__ FB1,
                   const float* __restrict__ FW2, const float* __restrict__ FB2,
                   float* __restrict__ Y)
{
    __shared__ float fin[BR][384];
    __shared__ float h[BR][256];
    const int t = threadIdx.x;
    const int row0 = blockIdx.x * BR;

    for (int i = t; i < BR * 384; i += 256) {
        int r = i / 384, c = i % 384;
        int row = row0 + r;
        fin[r][c] = (c < 256) ? x1[(size_t)row * D + c]
                              : m[(size_t)row * MDIM + (c - 256)];
    }
    __syncthreads();

    float a[BR];
#pragma unroll
    for (int r = 0; r < BR; ++r) a[r] = 0.f;
    for (int k = 0; k < 384; k += 4) {
        float w0 = FW1[(size_t)(k + 0) * D + t];
        float w1 = FW1[(size_t)(k + 1) * D + t];
        float w2 = FW1[(size_t)(k + 2) * D + t];
        float w3 = FW1[(size_t)(k + 3) * D + t];
#pragma unroll
        for (int r = 0; r < BR; ++r) {
            float4 xv = *reinterpret_cast<const float4*>(&fin[r][k]);
            a[r] = fmaf(xv.x, w0, a[r]);
            a[r] = fmaf(xv.y, w1, a[r]);
            a[r] = fmaf(xv.z, w2, a[r]);
            a[r] = fmaf(xv.w, w3, a[r]);
        }
    }
    float fb = FB1[t];
#pragma unroll
    for (int r = 0; r < BR; ++r) h[r][t] = fmaxf(a[r] + fb, 0.f);
    __syncthreads();

    float a2[BR];
#pragma unroll
    for (int r = 0; r < BR; ++r) a2[r] = 0.f;
    for (int k = 0; k < D; k += 4) {
        float w0 = FW2[(size_t)(k + 0) * D + t];
        float w1 = FW2[(size_t)(k + 1) * D + t];
        float w2 = FW2[(size_t)(k + 2) * D + t];
        float w3 = FW2[(size_t)(k + 3) * D + t];
#pragma unroll
        for (int r = 0; r < BR; ++r) {
            float4 hv = *reinterpret_cast<const float4*>(&h[r][k]);
            a2[r] = fmaf(hv.x, w0, a2[r]);
            a2[r] = fmaf(hv.y, w1, a2[r]);
            a2[r] = fmaf(hv.z, w2, a2[r]);
            a2[r] = fmaf(hv.w, w3, a2[r]);
        }
    }
    float fb2v = FB2[t];
#pragma unroll
    for (int r = 0; r < BR; ++r) {
        Y[(size_t)(row0 + r) * D + t] = a2[r] + fb2v;
    }
}

// ---------------------------------------------------------------------------
// Kalman: replicate the reference fp32 op sequence. innov == 0 exactly, so
// state = [z, 0]. cov = mask ? I8 : Pn (Pn computed per reference ops).
// ---------------------------------------------------------------------------
__global__ __launch_bounds__(256)
void kalman_kernel(const float* __restrict__ boxes, const int* __restrict__ masks,
                   float* __restrict__ st, float* __restrict__ cov)
{
    int i = blockIdx.x * blockDim.x + threadIdx.x;
    if (i >= NTRACK) return;
    int n = i % NB;
    int bg = i / NB;
    size_t rowlast = ((size_t)bg * TT + (TT - 1)) * NB + n;

    float z[4];
#pragma unroll
    for (int j = 0; j < 4; ++j) z[j] = boxes[rowlast * 4 + j];
    int mask = masks[rowlast];

#pragma unroll
    for (int j = 0; j < 4; ++j) st[(size_t)i * 8 + j] = z[j];
#pragma unroll
    for (int j = 4; j < 8; ++j) st[(size_t)i * 8 + j] = 0.0f;

    float C[8][8];
    if (mask != 0) {
#pragma unroll
        for (int a = 0; a < 8; ++a)
#pragma unroll
            for (int b = 0; b < 8; ++b) C[a][b] = (a == b) ? 1.0f : 0.0f;
    } else {
        // F = I8 with F[i][i+4]=1 (i<4); P0=I8
        float Pp[8][8];
#pragma unroll
        for (int a = 0; a < 8; ++a) {
#pragma unroll
            for (int b = 0; b < 8; ++b) {
                float s = 0.f;
#pragma unroll
                for (int k = 0; k < 8; ++k) {
                    float Fa = (a == k ? 1.f : 0.f) + ((a < 4 && k == a + 4) ? 1.f : 0.f);
                    float Fb = (b == k ? 1.f : 0.f) + ((b < 4 && k == b + 4) ? 1.f : 0.f);
                    s = fmaf(Fa, Fb, s);
                }
                Pp[a][b] = s + ((a == b) ? 0.01f : 0.0f);
            }
        }
        float S[4];
#pragma unroll
        for (int j = 0; j < 4; ++j) S[j] = Pp[j][j] + 0.1f;
        float K[8][4];
#pragma unroll
        for (int a = 0; a < 8; ++a)
#pragma unroll
            for (int j = 0; j < 4; ++j) K[a][j] = Pp[a][j] / S[j];
#pragma unroll
        for (int a = 0; a < 8; ++a) {
#pragma unroll
            for (int b = 0; b < 8; ++b) {
                float s = 0.f;
#pragma unroll
                for (int r = 0; r < 4; ++r) s = fmaf(K[a][r], Pp[r][b], s);
                C[a][b] = Pp[a][b] - s;
            }
        }
    }
#pragma unroll
    for (int a = 0; a < 8; ++a)
#pragma unroll
        for (int b = 0; b < 8; ++b) cov[(size_t)i * 64 + a * 8 + b] = C[a][b];
}

// ---------------------------------------------------------------------------
extern "C" void kernel_launch(void* const* d_in, const int* in_sizes, int n_in,
                              void* d_out, int out_size, void* d_ws, size_t ws_size,
                              hipStream_t stream)
{
    const float* feats = (const float*)d_in[0];
    const float* boxes = (const float*)d_in[1];
    const int*   masks = (const int*)d_in[2];
    const float* aw1 = (const float*)d_in[3];
    const float* ab1 = (const float*)d_in[4];
    const float* aw2 = (const float*)d_in[5];
    const float* ab2 = (const float*)d_in[6];
    const float* ng  = (const float*)d_in[7];
    const float* nb  = (const float*)d_in[8];
    const float* mw1 = (const float*)d_in[9];
    const float* mb1 = (const float*)d_in[10];
    const float* mw2 = (const float*)d_in[11];
    const float* mb2 = (const float*)d_in[12];
    const float* mw3 = (const float*)d_in[13];
    const float* mb3 = (const float*)d_in[14];
    const float* fw1 = (const float*)d_in[15];
    const float* fb1 = (const float*)d_in[16];
    const float* fw2 = (const float*)d_in[17];
    const float* fb2 = (const float*)d_in[18];
    const float* w1  = (const float*)d_in[19];
    const float* b1  = (const float*)d_in[20];
    const float* w2  = (const float*)d_in[21];
    const float* b2  = (const float*)d_in[22];
    const float* fng = (const float*)d_in[23];
    const float* fnb = (const float*)d_in[24];

    float* outx   = (float*)d_out;                       // R*256 — also working buf
    float* outst  = outx + (size_t)R_TOTAL * D;          // 4000*8
    float* outcov = outst + (size_t)NTRACK * 8;          // 4000*64

    float* m = (float*)d_ws;                             // R*128 floats = 32.8 MB

    // 1) x = feats + FFN(feats)         -> outx
    ffn_kernel<16><<<R_TOTAL / 16, 256, 0, stream>>>(feats, aw1, ab1, aw2, ab2, outx);
    // 2) x = LN(x)                      in-place
    ln_kernel<<<R_TOTAL / 4, 256, 0, stream>>>(outx, ng, nb, outx);
    // 3) m branch                       -> ws
    motion_kernel<16><<<R_TOTAL / 16, 128, 0, stream>>>(outx, boxes, masks,
                                                        mw1, mb1, mw2, mb2, mw3, mb3, m);
    // 4) fusion MLP                     in-place on outx
    fusion_kernel<16><<<R_TOTAL / 16, 256, 0, stream>>>(outx, m, fw1, fb1, fw2, fb2, outx);
    // 5) x = x + FFN(x)                 in-place
    ffn_kernel<16><<<R_TOTAL / 16, 256, 0, stream>>>(outx, w1, b1, w2, b2, outx);
    // 6) x = LN(x)                      in-place
    ln_kernel<<<R_TOTAL / 4, 256, 0, stream>>>(outx, fng, fnb, outx);
    // 7) Kalman                         -> out tail
    kalman_kernel<<<(NTRACK + 255) / 256, 256, 0, stream>>>(boxes, masks, outst, outcov);
}